// Round 6
// baseline (390.143 us; speedup 1.0000x reference)
//
#include <hip/hip_runtime.h>
#include <hip/hip_fp16.h>

#define BATCH 4
#define NSEQ 2048
#define DMODEL 512
#define NHEAD 8
#define HDIM 64
#define LSEL 32
#define SROWU 2056    // u16 elements per score row (2048 + 8 pad)
#define MAXL 128
#define QROWS 8       // q-rows per block

typedef __attribute__((ext_vector_type(8))) _Float16 f16x8;
typedef __attribute__((ext_vector_type(4))) float f32x4;

__device__ inline ushort f2h(float x) { __half h = __float2half(x); return *reinterpret_cast<ushort*>(&h); }
__device__ inline uint h2sort(ushort h) { return (h & 0x8000u) ? (uint)(h ^ 0xFFFFu) : (uint)(h | 0x8000u); }
__device__ inline float sort2f(uint su) {
    ushort hb = (su & 0x8000u) ? (ushort)(su ^ 0x8000u) : (ushort)(su ^ 0xFFFFu);
    __half th; *reinterpret_cast<ushort*>(&th) = hb;
    return __half2float(th);
}

// ---------------------------------------------------------------------------
// cvtW: W[512][512] fp32 -> Wt[n][k] fp16 (transposed), 4 matrices
// ---------------------------------------------------------------------------
__global__ __launch_bounds__(256) void cvtW_kernel(
    const float* __restrict__ Wq, const float* __restrict__ Wk,
    const float* __restrict__ Wv, const float* __restrict__ Wfc,
    ushort* __restrict__ Wt)
{
    const int z = blockIdx.y;
    const float* W = (z == 0) ? Wq : (z == 1) ? Wk : (z == 2) ? Wv : Wfc;
    ushort* O = Wt + (size_t)z * DMODEL * DMODEL;
    const int gt = blockIdx.x * 256 + threadIdx.x;
    const int n = gt & 511;
    const int kc = (gt >> 9) * 16;
    uint pk[8];
#pragma unroll
    for (int i = 0; i < 8; ++i) {
        uint lo = f2h(W[(size_t)(kc + 2 * i) * DMODEL + n]);
        uint hi = f2h(W[(size_t)(kc + 2 * i + 1) * DMODEL + n]);
        pk[i] = lo | (hi << 16);
    }
    uint4 u0 = {pk[0], pk[1], pk[2], pk[3]};
    uint4 u1 = {pk[4], pk[5], pk[6], pk[7]};
    *(uint4*)(O + (size_t)n * DMODEL + kc) = u0;
    *(uint4*)(O + (size_t)n * DMODEL + kc + 8) = u1;
}

// ---------------------------------------------------------------------------
// hgemm: OUT[8192,512] = A[8192,512] @ W (Wt stored [n][k] fp16).
// BM=64, BN=512, BK=32; 4 waves each 64x128; 16x16x32 f16 MFMA.
// MODE 0: A = fp32 (q/k/v), converted in-register; head-split fp16 out.
// MODE 1: A = fp16 (ao); fp32 row-major out.
// ---------------------------------------------------------------------------
template<int MODE>
__global__ __launch_bounds__(256, 2) void hgemm_kernel(
    const float* __restrict__ Fq, const float* __restrict__ Fk, const float* __restrict__ Fv,
    const ushort* __restrict__ A16,
    const ushort* __restrict__ Wt,
    ushort* __restrict__ O0, ushort* __restrict__ O1, ushort* __restrict__ O2,
    float* __restrict__ Ofc)
{
    __shared__ ushort Ah[64][40];
    __shared__ ushort Bh[512][40];   // also reused as epilogue staging

    const int tid = threadIdx.x;
    const int wave = tid >> 6, lane = tid & 63;
    const int lr = lane & 15, lg = lane >> 4;
    const int bm = blockIdx.x * 64;
    const int z = blockIdx.y;

    const float* Af = (MODE == 0) ? (z == 0 ? Fq : z == 1 ? Fk : Fv) : nullptr;
    const ushort* Wz = Wt + (size_t)((MODE == 0) ? z : 3) * (DMODEL * DMODEL);

    f32x4 acc[4][8];
#pragma unroll
    for (int i = 0; i < 4; ++i)
#pragma unroll
        for (int j = 0; j < 8; ++j) acc[i][j] = (f32x4){0.f, 0.f, 0.f, 0.f};

    const int sar = tid >> 2, sak = (tid & 3) * 8;

    for (int k0 = 0; k0 < DMODEL; k0 += 32) {
        __syncthreads();
        if (MODE == 0) {
            float4 fa = *(const float4*)(Af + (size_t)(bm + sar) * DMODEL + k0 + sak);
            float4 fb = *(const float4*)(Af + (size_t)(bm + sar) * DMODEL + k0 + sak + 4);
            uint4 pk;
            pk.x = (uint)f2h(fa.x) | ((uint)f2h(fa.y) << 16);
            pk.y = (uint)f2h(fa.z) | ((uint)f2h(fa.w) << 16);
            pk.z = (uint)f2h(fb.x) | ((uint)f2h(fb.y) << 16);
            pk.w = (uint)f2h(fb.z) | ((uint)f2h(fb.w) << 16);
            *(uint4*)&Ah[sar][sak] = pk;
        } else {
            *(uint4*)&Ah[sar][sak] = *(const uint4*)(A16 + (size_t)(bm + sar) * DMODEL + k0 + sak);
        }
#pragma unroll
        for (int i = 0; i < 8; ++i) {
            int n = sar + 64 * i;
            *(uint4*)&Bh[n][sak] = *(const uint4*)(Wz + (size_t)n * DMODEL + k0 + sak);
        }
        __syncthreads();
        f16x8 af[4];
#pragma unroll
        for (int fr = 0; fr < 4; ++fr) af[fr] = *(const f16x8*)&Ah[fr * 16 + lr][lg * 8];
#pragma unroll
        for (int fc2 = 0; fc2 < 8; ++fc2) {
            f16x8 bf = *(const f16x8*)&Bh[wave * 128 + fc2 * 16 + lr][lg * 8];
#pragma unroll
            for (int fr = 0; fr < 4; ++fr)
                acc[fr][fc2] = __builtin_amdgcn_mfma_f32_16x16x32_f16(af[fr], bf, acc[fr][fc2], 0, 0, 0);
        }
    }

    if (MODE == 1) {
#pragma unroll
        for (int fr = 0; fr < 4; ++fr)
#pragma unroll
            for (int fc2 = 0; fc2 < 8; ++fc2)
#pragma unroll
                for (int r = 0; r < 4; ++r)
                    Ofc[(size_t)(bm + fr * 16 + lg * 4 + r) * DMODEL + wave * 128 + fc2 * 16 + lr] = acc[fr][fc2][r];
        return;
    }

    // MODE 0 epilogue: LDS transpose -> coalesced head-split fp16 stores
    ushort* O = (z == 0) ? O0 : (z == 1) ? O1 : O2;
    const int b = bm >> 11;
    const int nseq0 = bm & (NSEQ - 1);
    ushort* smw = (ushort*)&Bh[0][0] + wave * (64 * 72);
#pragma unroll
    for (int hp = 0; hp < 2; ++hp) {
        __syncthreads();
#pragma unroll
        for (int f4 = 0; f4 < 4; ++f4) {
            int fc2 = hp * 4 + f4;
            int nl = f4 * 16 + lr;
#pragma unroll
            for (int fr = 0; fr < 4; ++fr)
#pragma unroll
                for (int r = 0; r < 4; ++r)
                    smw[(fr * 16 + lg * 4 + r) * 72 + nl] = f2h(acc[fr][fc2][r]);
        }
        __syncthreads();
        const int h = wave * 2 + hp;
        ushort* obase = O + ((size_t)(b * NHEAD + h) * NSEQ + nseq0) * HDIM;
#pragma unroll
        for (int i = 0; i < 8; ++i) {
            int m = i * 8 + (lane >> 3);
            int dc = (lane & 7) * 8;
            *(uint4*)(obase + (size_t)m * HDIM + dc) = *(const uint4*)(smw + m * 72 + dc);
        }
    }
}

// ---------------------------------------------------------------------------
// attention helpers
// ---------------------------------------------------------------------------
__device__ inline int wave_sum6(int c) {
    int tot = (int)__popcll(__ballot(c & 1));
    tot += (int)__popcll(__ballot(c & 2)) << 1;
    tot += (int)__popcll(__ballot(c & 4)) << 2;
    tot += (int)__popcll(__ballot(c & 8)) << 3;
    tot += (int)__popcll(__ballot(c & 16)) << 4;
    tot += (int)__popcll(__ballot(c & 32)) << 5;
    return tot;
}

__device__ uint full_thr(const ushort* Sr, int lane, uint lo0) {
    uint flo = lo0, fhi = 0xFFFFu;
#pragma unroll 1
    for (int it2 = 0; it2 < 16; ++it2) {
        uint mid = (flo + fhi + 1) >> 1, M = mid << 16;
        int cl = 0;
#pragma unroll
        for (int it = 0; it < 4; ++it) {
            uint4 r4 = *(const uint4*)(Sr + it * 512 + lane * 8);
            cl += ((r4.x << 16) >= M) + ((r4.x & 0xFFFF0000u) >= M);
            cl += ((r4.y << 16) >= M) + ((r4.y & 0xFFFF0000u) >= M);
            cl += ((r4.z << 16) >= M) + ((r4.z & 0xFFFF0000u) >= M);
            cl += ((r4.w << 16) >= M) + ((r4.w & 0xFFFF0000u) >= M);
        }
        bool ge = wave_sum6(cl) >= LSEL;
        flo = ge ? mid : flo;
        fhi = ge ? fhi : mid - 1;
    }
    return flo;
}

__device__ int recount(const ushort* Sr, int lane, uint th) {
    int cs = 0;
#pragma unroll
    for (int it = 0; it < 4; ++it) {
        uint4 r4 = *(const uint4*)(Sr + it * 512 + lane * 8);
        cs += ((r4.x << 16) >= th) + ((r4.x & 0xFFFF0000u) >= th);
        cs += ((r4.y << 16) >= th) + ((r4.y & 0xFFFF0000u) >= th);
        cs += ((r4.z << 16) >= th) + ((r4.z & 0xFFFF0000u) >= th);
        cs += ((r4.w << 16) >= th) + ((r4.w & 0xFFFF0000u) >= th);
    }
    return cs;
}

// slow-path extraction: full row scan, lane-major order
__device__ float extract_big(const ushort* Sr, int lane, uint th, float Mv,
                             int pre, ushort* li, float* lwp)
{
    const float L2E = 1.4426950408889634f;
    float wp = 0.f;
    int pos = pre;
#pragma unroll
    for (int it = 0; it < 4; ++it) {
        uint4 r4 = *(const uint4*)(Sr + it * 512 + lane * 8);
        uint ib = (uint)(it * 512 + lane * 8);
        uint wds[4] = {r4.x, r4.y, r4.z, r4.w};
#pragma unroll
        for (int c = 0; c < 4; ++c) {
            uint vL = wds[c] << 16, vH = wds[c] & 0xFFFF0000u;
            if (vL >= th) {
                float w = exp2f((sort2f(vL >> 16) - Mv) * L2E);
                if (pos < MAXL) { li[pos] = (ushort)(ib + c * 2); lwp[pos] = w; wp += w; }
                ++pos;
            }
            if (vH >= th) {
                float w = exp2f((sort2f(vH >> 16) - Mv) * L2E);
                if (pos < MAXL) { li[pos] = (ushort)(ib + c * 2 + 1); lwp[pos] = w; wp += w; }
                ++pos;
            }
        }
    }
#pragma unroll
    for (int off = 32; off >= 1; off >>= 1) wp += __shfl_xor(wp, off);
    return wp;
}

// fast-path extraction: selected values are the lane's sorted top-4 prefix
__device__ float extract_fast(uint t0, uint t1, uint t2, uint t3,
                              uint th, float Mv, int pre, ushort* li, float* lwp)
{
    const float L2E = 1.4426950408889634f;
    float wp = 0.f;
    uint tt[4] = {t0, t1, t2, t3};
#pragma unroll
    for (int i = 0; i < 4; ++i) {
        if (tt[i] >= th) {
            int pos = pre + i;
            float w = exp2f((sort2f(tt[i] >> 16) - Mv) * L2E);
            if (pos < MAXL) { li[pos] = (ushort)(tt[i] & 0xFFFFu); lwp[pos] = w; wp += w; }
        }
    }
#pragma unroll
    for (int off = 32; off >= 1; off >>= 1) wp += __shfl_xor(wp, off);
    return wp;
}

#define INS5(T0, T1, T2, T3, T4, P) { \
    uint m1_ = min(P, T0); T0 = max(P, T0); \
    uint m2_ = min(m1_, T1); T1 = max(m1_, T1); \
    uint m3_ = min(m2_, T2); T2 = max(m2_, T2); \
    uint m4_ = min(m3_, T3); T3 = max(m3_, T3); \
    T4 = max(m4_, T4); }

// ---------------------------------------------------------------------------
// attn v6: 8 q-rows/block (~39KB LDS -> 4 blocks/CU = 100% occupancy).
// Phase 1: wave w computes keys [256w,256w+256) x 8 q-rows (B cols duplicated).
// Phase 2: one q-row per wave; top-5 prepass; ballot binary search on the
// 256-value sample; exactness via 5th-largest; register fast-path extraction.
// PV: full wave = 32 half2-dims x 2-way key split, shfl(32) combine.
// ---------------------------------------------------------------------------
__global__ __launch_bounds__(512, 8) void attn_kernel(
    const ushort* __restrict__ qh, const ushort* __restrict__ kh,
    const ushort* __restrict__ vh, ushort* __restrict__ ao)
{
    __shared__ __align__(16) ushort Sbuf[QROWS * SROWU];
    __shared__ ushort lidx[QROWS][MAXL];
    __shared__ float  lw[QROWS][MAXL];

    const int tid = threadIdx.x;
    const int wave = tid >> 6;
    const int lane = tid & 63;
    const int bh = blockIdx.y;
    const int q0 = blockIdx.x * QROWS;
    const int lr = lane & 15;
    const int lg = lane >> 4;

    const ushort* Qb = qh + ((size_t)bh * NSEQ + q0) * HDIM;
    const ushort* Kb = kh + (size_t)bh * NSEQ * HDIM;

    // B operand: cols 0-7 = q-rows, cols 8-15 duplicate (ignored on store)
    f16x8 qf0 = *(const f16x8*)(Qb + (lr & 7) * HDIM + lg * 8);
    f16x8 qf1 = *(const f16x8*)(Qb + (lr & 7) * HDIM + 32 + lg * 8);

    // -------- Phase 1: scores --------
    for (int t = 0; t < 16; ++t) {
        const int k0 = wave * 256 + t * 16;
        const ushort* Kt = Kb + (size_t)k0 * HDIM;
        f16x8 a0 = *(const f16x8*)(Kt + lr * HDIM + lg * 8);
        f16x8 a1 = *(const f16x8*)(Kt + lr * HDIM + 32 + lg * 8);
        f32x4 acc = {0.f, 0.f, 0.f, 0.f};
        acc = __builtin_amdgcn_mfma_f32_16x16x32_f16(a0, qf0, acc, 0, 0, 0);
        acc = __builtin_amdgcn_mfma_f32_16x16x32_f16(a1, qf1, acc, 0, 0, 0);
        if (lr < QROWS) {
            uint2 pk;
            pk.x = h2sort(f2h(acc[0] * 0.125f)) | (h2sort(f2h(acc[1] * 0.125f)) << 16);
            pk.y = h2sort(f2h(acc[2] * 0.125f)) | (h2sort(f2h(acc[3] * 0.125f)) << 16);
            *(uint2*)&Sbuf[lr * SROWU + k0 + lg * 4] = pk;
        }
    }
    __syncthreads();

    // -------- Phase 2: one q-row per wave --------
    const ushort* Vb = vh + (size_t)bh * NSEQ * HDIM;
    const int b = bh >> 3, hh = bh & 7;
    const unsigned long long below = (1ULL << lane) - 1ULL;

    const int qr = wave;
    const ushort* Sr = &Sbuf[qr * SROWU];

    // top-5 packed (val<<16|idx) prepass
    uint a0 = 0, a1 = 0, a2 = 0, a3 = 0, a4 = 0;
#pragma unroll
    for (int it = 0; it < 4; ++it) {
        uint4 ra = *(const uint4*)(Sr + it * 512 + lane * 8);
        uint ib = (uint)(it * 512 + lane * 8);
        uint p;
        p = (ra.x << 16) | (ib + 0); INS5(a0, a1, a2, a3, a4, p);
        p = (ra.x & 0xFFFF0000u) | (ib + 1); INS5(a0, a1, a2, a3, a4, p);
        p = (ra.y << 16) | (ib + 2); INS5(a0, a1, a2, a3, a4, p);
        p = (ra.y & 0xFFFF0000u) | (ib + 3); INS5(a0, a1, a2, a3, a4, p);
        p = (ra.z << 16) | (ib + 4); INS5(a0, a1, a2, a3, a4, p);
        p = (ra.z & 0xFFFF0000u) | (ib + 5); INS5(a0, a1, a2, a3, a4, p);
        p = (ra.w << 16) | (ib + 6); INS5(a0, a1, a2, a3, a4, p);
        p = (ra.w & 0xFFFF0000u) | (ib + 7); INS5(a0, a1, a2, a3, a4, p);
    }

    // wave max (exp shift)
    uint mx = a0;
#pragma unroll
    for (int off = 32; off >= 1; off >>= 1) mx = max(mx, (uint)__shfl_xor((int)mx, off));
    const float Mv = sort2f(mx >> 16);

    // binary search: 32nd largest of the 256-value top-4 sample
    uint lo = 0, hi = 0xFFFFu;
#pragma unroll
    for (int it = 0; it < 16; ++it) {
        uint mid = (lo + hi + 1) >> 1, M = mid << 16;
        int c = (a0 >= M) + (a1 >= M) + (a2 >= M) + (a3 >= M);
        int tot = (int)__popcll(__ballot(c & 1)) + ((int)__popcll(__ballot(c & 2)) << 1)
                + ((int)__popcll(__ballot(c & 4)) << 2);
        bool ge = tot >= LSEL;
        lo = ge ? mid : lo;
        hi = ge ? hi : mid - 1;
    }
    uint th = lo << 16;

    // exactness: sample complete iff no lane's 5th-largest >= thr
    const bool miss = __any(a4 >= th);

    int csel;
    if (!miss) {
        csel = (a0 >= th) + (a1 >= th) + (a2 >= th) + (a3 >= th);
    } else {
        int cgt = recount(Sr, lane, th + 0x10000u);       // count( > lo )
        if (wave_sum6(cgt) >= LSEL) { lo = full_thr(Sr, lane, lo); th = lo << 16; }
        csel = recount(Sr, lane, th);
    }

    // lane prefix + total (6-bit ballots)
    int pre = 0, totsel = 0;
#pragma unroll
    for (int bb = 0; bb < 6; ++bb) {
        unsigned long long m = __ballot((csel >> bb) & 1);
        pre += (int)__popcll(m & below) << bb;
        totsel += (int)__popcll(m) << bb;
    }

    const float wsum = miss
        ? extract_big(Sr, lane, th, Mv, pre, &lidx[qr][0], &lw[qr][0])
        : extract_fast(a0, a1, a2, a3, th, Mv, pre, &lidx[qr][0], &lw[qr][0]);

    const int nk = (totsel < MAXL) ? totsel : MAXL;

    asm volatile("s_waitcnt lgkmcnt(0)" ::: "memory");

    // -------- sparse PV: 32 half2-dims x 2-way key split --------
    const int half = lane >> 5;            // key parity
    const int dp = lane & 31;              // dim pair
    const __half2* V2 = reinterpret_cast<const __half2*>(Vb);

    float ox = 0.f, oy = 0.f;
    int j = half;
    for (; j + 6 < nk; j += 8) {
        int i0 = lidx[qr][j + 0]; float w0 = lw[qr][j + 0];
        int i1 = lidx[qr][j + 2]; float w1 = lw[qr][j + 2];
        int i2 = lidx[qr][j + 4]; float w2 = lw[qr][j + 4];
        int i3 = lidx[qr][j + 6]; float w3 = lw[qr][j + 6];
        float2 v0 = __half22float2(V2[(size_t)i0 * 32 + dp]);
        float2 v1 = __half22float2(V2[(size_t)i1 * 32 + dp]);
        float2 v2 = __half22float2(V2[(size_t)i2 * 32 + dp]);
        float2 v3 = __half22float2(V2[(size_t)i3 * 32 + dp]);
        ox += w0 * v0.x + w1 * v1.x + w2 * v2.x + w3 * v3.x;
        oy += w0 * v0.y + w1 * v1.y + w2 * v2.y + w3 * v3.y;
    }
    for (; j < nk; j += 2) {
        int i0 = lidx[qr][j]; float w0 = lw[qr][j];
        float2 v0 = __half22float2(V2[(size_t)i0 * 32 + dp]);
        ox += w0 * v0.x; oy += w0 * v0.y;
    }
    ox += __shfl_xor(ox, 32);
    oy += __shfl_xor(oy, 32);

    if (half == 0) {
        const float inv = 1.f / wsum;
        uint opk = (uint)f2h(ox * inv) | ((uint)f2h(oy * inv) << 16);
        *(uint*)(ao + ((size_t)(b * NSEQ) + q0 + qr) * DMODEL + hh * HDIM + dp * 2) = opk;
    }
}

// ---------------------------------------------------------------------------
// LN: out = LN(fc_raw + resid) * g + b ; 4 waves/block, 1 row/wave
// ---------------------------------------------------------------------------
__global__ __launch_bounds__(256) void ln_kernel(
    const float* __restrict__ fcr, const float* __restrict__ resid,
    const float* __restrict__ g, const float* __restrict__ bta, float* __restrict__ out)
{
    const int row = blockIdx.x * 4 + (threadIdx.x >> 6);
    const int lane = threadIdx.x & 63;
    const size_t base = (size_t)row * DMODEL + lane * 8;
    float4 xa = *(const float4*)(fcr + base);
    float4 xb = *(const float4*)(fcr + base + 4);
    float4 ra = *(const float4*)(resid + base);
    float4 rb = *(const float4*)(resid + base + 4);
    xa.x += ra.x; xa.y += ra.y; xa.z += ra.z; xa.w += ra.w;
    xb.x += rb.x; xb.y += rb.y; xb.z += rb.z; xb.w += rb.w;
    float sum = xa.x + xa.y + xa.z + xa.w + xb.x + xb.y + xb.z + xb.w;
    float sq = xa.x * xa.x + xa.y * xa.y + xa.z * xa.z + xa.w * xa.w
             + xb.x * xb.x + xb.y * xb.y + xb.z * xb.z + xb.w * xb.w;
#pragma unroll
    for (int off = 32; off >= 1; off >>= 1) {
        sum += __shfl_xor(sum, off);
        sq += __shfl_xor(sq, off);
    }
    float mean = sum * (1.f / 512.f);
    float var = sq * (1.f / 512.f) - mean * mean;
    float rstd = rsqrtf(var + 1e-6f);
    float4 ga = *(const float4*)(g + lane * 8);
    float4 gb = *(const float4*)(g + lane * 8 + 4);
    float4 ba = *(const float4*)(bta + lane * 8);
    float4 bb = *(const float4*)(bta + lane * 8 + 4);
    float4 oa, ob;
    oa.x = (xa.x - mean) * rstd * ga.x + ba.x;
    oa.y = (xa.y - mean) * rstd * ga.y + ba.y;
    oa.z = (xa.z - mean) * rstd * ga.z + ba.z;
    oa.w = (xa.w - mean) * rstd * ga.w + ba.w;
    ob.x = (xb.x - mean) * rstd * gb.x + bb.x;
    ob.y = (xb.y - mean) * rstd * gb.y + bb.y;
    ob.z = (xb.z - mean) * rstd * gb.z + bb.z;
    ob.w = (xb.w - mean) * rstd * gb.w + bb.w;
    *(float4*)(out + base) = oa;
    *(float4*)(out + base + 4) = ob;
}

extern "C" void kernel_launch(void* const* d_in, const int* in_sizes, int n_in,
                              void* d_out, int out_size, void* d_ws, size_t ws_size,
                              hipStream_t stream)
{
    (void)in_sizes; (void)n_in; (void)out_size; (void)ws_size;

    const float* q   = (const float*)d_in[0];
    const float* k   = (const float*)d_in[1];
    const float* v   = (const float*)d_in[2];
    const float* Wq  = (const float*)d_in[3];
    const float* Wk  = (const float*)d_in[4];
    const float* Wv  = (const float*)d_in[5];
    const float* Wfc = (const float*)d_in[6];
    const float* g   = (const float*)d_in[7];
    const float* b   = (const float*)d_in[8];
    float* out = (float*)d_out;

    const size_t SZ = (size_t)BATCH * NSEQ * DMODEL;      // 4,194,304
    const size_t WSZ = (size_t)DMODEL * DMODEL;           // 262,144
    ushort* Wt = (ushort*)d_ws;                           // 4 matrices, 2 MB
    ushort* qh = Wt + 4 * WSZ;
    ushort* kh = qh + SZ;
    ushort* vh = kh + SZ;
    ushort* ao = vh + SZ;
    float* fc_raw = (float*)qh;   // overlays qh+kh (dead after attn)

    cvtW_kernel<<<dim3(64, 4), 256, 0, stream>>>(Wq, Wk, Wv, Wfc, Wt);
    hgemm_kernel<0><<<dim3(128, 3), 256, 0, stream>>>(q, k, v, nullptr, Wt, qh, kh, vh, nullptr);
    attn_kernel<<<dim3(NSEQ / QROWS, BATCH * NHEAD), 512, 0, stream>>>(qh, kh, vh, ao);
    hgemm_kernel<1><<<dim3(128, 1), 256, 0, stream>>>(nullptr, nullptr, nullptr, ao, Wt, nullptr, nullptr, nullptr, fc_raw);
    ln_kernel<<<(BATCH * NSEQ) / 4, 256, 0, stream>>>(fc_raw, q, g, b, out);
}

// Round 7
// 324.731 us; speedup vs baseline: 1.2014x; 1.2014x over previous
//
#include <hip/hip_runtime.h>
#include <hip/hip_fp16.h>

#define BATCH 4
#define NSEQ 2048
#define DMODEL 512
#define NHEAD 8
#define HDIM 64
#define LSEL 32
#define SROWU 2056    // u16 per score row (2048 + 8 pad, 16B-aligned rows)
#define MAXL 64
#define QROWS 16
#define CSTRIDE 165   // cand row stride in u32 (5*33)

typedef __attribute__((ext_vector_type(8))) _Float16 f16x8;
typedef __attribute__((ext_vector_type(4))) float f32x4;
typedef unsigned long long ull;

__device__ inline ushort f2h(float x) { __half h = __float2half(x); return *reinterpret_cast<ushort*>(&h); }
__device__ inline float h16f(ushort u) { __half t; *reinterpret_cast<ushort*>(&t) = u; return __half2float(t); }
__device__ inline float sort2f(uint su) {
    ushort hb = (su & 0x8000u) ? (ushort)(su ^ 0x8000u) : (ushort)(su ^ 0xFFFFu);
    return h16f(hb);
}
// packed sortable map: per u16 half, neg -> ^0xFFFF, pos -> |0x8000
__device__ inline uint sm2(uint w) {
    uint s = (w >> 15) & 0x00010001u;
    uint m = s * 0x7FFFu;
    return w ^ (m | 0x80008000u);
}

// ---------------------------------------------------------------------------
// cvtA: fp32 -> fp16 copies of q,k,v
// ---------------------------------------------------------------------------
__global__ __launch_bounds__(256) void cvtA_kernel(
    const float* __restrict__ q, const float* __restrict__ k, const float* __restrict__ v,
    ushort* __restrict__ q16, ushort* __restrict__ k16, ushort* __restrict__ v16)
{
    const int z = blockIdx.y;
    const float* src = (z == 0) ? q : (z == 1) ? k : v;
    ushort* dst = (z == 0) ? q16 : (z == 1) ? k16 : v16;
    const size_t base = (size_t)blockIdx.x * 2048 + threadIdx.x * 4;
    float4 fa = *(const float4*)(src + base);
    float4 fb = *(const float4*)(src + base + 1024);
    ushort4 ha = {f2h(fa.x), f2h(fa.y), f2h(fa.z), f2h(fa.w)};
    ushort4 hb = {f2h(fb.x), f2h(fb.y), f2h(fb.z), f2h(fb.w)};
    *(ushort4*)(dst + base) = ha;
    *(ushort4*)(dst + base + 1024) = hb;
}

// ---------------------------------------------------------------------------
// cvtW: W[512][512] fp32 -> Wt[n][k] fp16 (transposed), 4 matrices
// ---------------------------------------------------------------------------
__global__ __launch_bounds__(256) void cvtW_kernel(
    const float* __restrict__ Wq, const float* __restrict__ Wk,
    const float* __restrict__ Wv, const float* __restrict__ Wfc,
    ushort* __restrict__ Wt)
{
    const int z = blockIdx.y;
    const float* W = (z == 0) ? Wq : (z == 1) ? Wk : (z == 2) ? Wv : Wfc;
    ushort* O = Wt + (size_t)z * DMODEL * DMODEL;
    const int gt = blockIdx.x * 256 + threadIdx.x;
    const int n = gt & 511;
    const int kc = (gt >> 9) * 16;
    uint pk[8];
#pragma unroll
    for (int i = 0; i < 8; ++i) {
        uint lo = f2h(W[(size_t)(kc + 2 * i) * DMODEL + n]);
        uint hi = f2h(W[(size_t)(kc + 2 * i + 1) * DMODEL + n]);
        pk[i] = lo | (hi << 16);
    }
    uint4 u0 = {pk[0], pk[1], pk[2], pk[3]};
    uint4 u1 = {pk[4], pk[5], pk[6], pk[7]};
    *(uint4*)(O + (size_t)n * DMODEL + kc) = u0;
    *(uint4*)(O + (size_t)n * DMODEL + kc + 8) = u1;
}

// ---------------------------------------------------------------------------
// hgemm: OUT[8192,512] = A16[8192,512] @ W (Wt stored [n][k] fp16).
// MODE 0: head-split fp16 out; z==0 (Q) pre-scaled by 0.125.
// MODE 1: fp32 row-major out.
// ---------------------------------------------------------------------------
template<int MODE>
__global__ __launch_bounds__(256, 2) void hgemm_kernel(
    const ushort* __restrict__ A0, const ushort* __restrict__ A1, const ushort* __restrict__ A2,
    const ushort* __restrict__ Wt,
    ushort* __restrict__ O0, ushort* __restrict__ O1, ushort* __restrict__ O2,
    float* __restrict__ Ofc)
{
    __shared__ ushort Ah[64][40];
    __shared__ ushort Bh[512][40];

    const int tid = threadIdx.x;
    const int wave = tid >> 6, lane = tid & 63;
    const int lr = lane & 15, lg = lane >> 4;
    const int bm = blockIdx.x * 64;
    const int z = blockIdx.y;

    const ushort* A16 = (MODE == 0) ? (z == 0 ? A0 : z == 1 ? A1 : A2) : A0;
    const ushort* Wz = Wt + (size_t)((MODE == 0) ? z : 3) * (DMODEL * DMODEL);

    f32x4 acc[4][8];
#pragma unroll
    for (int i = 0; i < 4; ++i)
#pragma unroll
        for (int j = 0; j < 8; ++j) acc[i][j] = (f32x4){0.f, 0.f, 0.f, 0.f};

    const int sar = tid >> 2, sak = (tid & 3) * 8;

    for (int k0 = 0; k0 < DMODEL; k0 += 32) {
        __syncthreads();
        *(uint4*)&Ah[sar][sak] = *(const uint4*)(A16 + (size_t)(bm + sar) * DMODEL + k0 + sak);
#pragma unroll
        for (int i = 0; i < 8; ++i) {
            int n = sar + 64 * i;
            *(uint4*)&Bh[n][sak] = *(const uint4*)(Wz + (size_t)n * DMODEL + k0 + sak);
        }
        __syncthreads();
        f16x8 af[4];
#pragma unroll
        for (int fr = 0; fr < 4; ++fr) af[fr] = *(const f16x8*)&Ah[fr * 16 + lr][lg * 8];
#pragma unroll
        for (int fc2 = 0; fc2 < 8; ++fc2) {
            f16x8 bf = *(const f16x8*)&Bh[wave * 128 + fc2 * 16 + lr][lg * 8];
#pragma unroll
            for (int fr = 0; fr < 4; ++fr)
                acc[fr][fc2] = __builtin_amdgcn_mfma_f32_16x16x32_f16(af[fr], bf, acc[fr][fc2], 0, 0, 0);
        }
    }

    if (MODE == 1) {
#pragma unroll
        for (int fr = 0; fr < 4; ++fr)
#pragma unroll
            for (int fc2 = 0; fc2 < 8; ++fc2)
#pragma unroll
                for (int r = 0; r < 4; ++r)
                    Ofc[(size_t)(bm + fr * 16 + lg * 4 + r) * DMODEL + wave * 128 + fc2 * 16 + lr] = acc[fr][fc2][r];
        return;
    }

    // MODE 0 epilogue: LDS transpose -> coalesced head-split fp16 stores
    const float osc = (z == 0) ? 0.125f : 1.0f;   // fold QK^T scale into Q
    ushort* O = (z == 0) ? O0 : (z == 1) ? O1 : O2;
    const int b = bm >> 11;
    const int nseq0 = bm & (NSEQ - 1);
    ushort* smw = (ushort*)&Bh[0][0] + wave * (64 * 72);
#pragma unroll
    for (int hp = 0; hp < 2; ++hp) {
        __syncthreads();
#pragma unroll
        for (int f4 = 0; f4 < 4; ++f4) {
            int fc2 = hp * 4 + f4;
            int nl = f4 * 16 + lr;
#pragma unroll
            for (int fr = 0; fr < 4; ++fr)
#pragma unroll
                for (int r = 0; r < 4; ++r)
                    smw[(fr * 16 + lg * 4 + r) * 72 + nl] = f2h(acc[fr][fc2][r] * osc);
        }
        __syncthreads();
        const int h = wave * 2 + hp;
        ushort* obase = O + ((size_t)(b * NHEAD + h) * NSEQ + nseq0) * HDIM;
#pragma unroll
        for (int i = 0; i < 8; ++i) {
            int m = i * 8 + (lane >> 3);
            int dc = (lane & 7) * 8;
            *(uint4*)(obase + (size_t)m * HDIM + dc) = *(const uint4*)(smw + m * 72 + dc);
        }
    }
}

// ---------------------------------------------------------------------------
// attention slow-path helpers (full-wave scans over a stored score row)
// ---------------------------------------------------------------------------
__device__ inline int wave_sum6(int c) {
    int tot = (int)__popcll(__ballot(c & 1));
    tot += (int)__popcll(__ballot(c & 2)) << 1;
    tot += (int)__popcll(__ballot(c & 4)) << 2;
    tot += (int)__popcll(__ballot(c & 8)) << 3;
    tot += (int)__popcll(__ballot(c & 16)) << 4;
    tot += (int)__popcll(__ballot(c & 32)) << 5;
    return tot;
}

__device__ uint full_thr(const ushort* Sr, int lane, uint lo0) {
    uint flo = lo0, fhi = 0xFFFFu;
#pragma unroll 1
    for (int it2 = 0; it2 < 16; ++it2) {
        uint mid = (flo + fhi + 1) >> 1, M = mid << 16;
        int cl = 0;
#pragma unroll
        for (int it = 0; it < 4; ++it) {
            uint4 r4 = *(const uint4*)(Sr + it * 512 + lane * 8);
            cl += ((r4.x << 16) >= M) + ((r4.x & 0xFFFF0000u) >= M);
            cl += ((r4.y << 16) >= M) + ((r4.y & 0xFFFF0000u) >= M);
            cl += ((r4.z << 16) >= M) + ((r4.z & 0xFFFF0000u) >= M);
            cl += ((r4.w << 16) >= M) + ((r4.w & 0xFFFF0000u) >= M);
        }
        bool ge = wave_sum6(cl) >= LSEL;
        flo = ge ? mid : flo;
        fhi = ge ? fhi : mid - 1;
    }
    return flo;
}

__device__ int recount(const ushort* Sr, int lane, uint th) {
    int cs = 0;
#pragma unroll
    for (int it = 0; it < 4; ++it) {
        uint4 r4 = *(const uint4*)(Sr + it * 512 + lane * 8);
        cs += ((r4.x << 16) >= th) + ((r4.x & 0xFFFF0000u) >= th);
        cs += ((r4.y << 16) >= th) + ((r4.y & 0xFFFF0000u) >= th);
        cs += ((r4.z << 16) >= th) + ((r4.z & 0xFFFF0000u) >= th);
        cs += ((r4.w << 16) >= th) + ((r4.w & 0xFFFF0000u) >= th);
    }
    return cs;
}

// full-row extraction (slow path): writes packed (w16<<16|idx), fp16-rounded wsum
__device__ float extract_big(const ushort* Sr, int lane, uint th, float Mv,
                             int pre, uint* selrow)
{
    const float L2E = 1.4426950408889634f;
    float wp = 0.f;
    int pos = pre;
#pragma unroll
    for (int it = 0; it < 4; ++it) {
        uint4 r4 = *(const uint4*)(Sr + it * 512 + lane * 8);
        uint ib = (uint)(it * 512 + lane * 8);
        uint wds[4] = {r4.x, r4.y, r4.z, r4.w};
#pragma unroll
        for (int c = 0; c < 4; ++c) {
            uint vL = wds[c] << 16, vH = wds[c] & 0xFFFF0000u;
            if (vL >= th) {
                ushort w16 = f2h(exp2f((sort2f(vL >> 16) - Mv) * L2E));
                if (pos < MAXL) { selrow[pos] = ((uint)w16 << 16) | (ib + c * 2); wp += h16f(w16); }
                ++pos;
            }
            if (vH >= th) {
                ushort w16 = f2h(exp2f((sort2f(vH >> 16) - Mv) * L2E));
                if (pos < MAXL) { selrow[pos] = ((uint)w16 << 16) | (ib + c * 2 + 1); wp += h16f(w16); }
                ++pos;
            }
        }
    }
#pragma unroll
    for (int off = 32; off >= 1; off >>= 1) wp += __shfl_xor(wp, off);
    return wp;
}

#define INS5(T0, T1, T2, T3, T4, P) { \
    uint m1_ = min(P, T0); T0 = max(P, T0); \
    uint m2_ = min(m1_, T1); T1 = max(m1_, T1); \
    uint m3_ = min(m2_, T2); T2 = max(m2_, T2); \
    uint m4_ = min(m3_, T3); T3 = max(m3_, T3); \
    T4 = max(m4_, T4); }

// ---------------------------------------------------------------------------
// attn v7: 16 q-rows/block, 8 waves.
// Phase 1: MFMA QK^T; ONLINE per-lane top-5 (4 indep packed structures, merged)
//          -> cand[row][5][32]; full sortable scores -> Sbuf (slow path only).
// Phase 2: 2 rows/wave (one per 32-lane half). Binary search over the 160
//          candidates (3 ballots/iter); exact iff no stream's 5th >= t-hat;
//          rare full-row slow path. sel = packed (w16|idx). PV 8-deep unroll.
// ---------------------------------------------------------------------------
__global__ __launch_bounds__(512, 4) void attn_kernel(
    const ushort* __restrict__ qh, const ushort* __restrict__ kh,
    const ushort* __restrict__ vh, ushort* __restrict__ ao)
{
    __shared__ __align__(16) ushort Sbuf[QROWS * SROWU];   // 65792 B
    __shared__ uint cand[QROWS * CSTRIDE];                 // 10560 B
    __shared__ __align__(16) uint sel[QROWS][MAXL];        // 4096 B

    const int tid = threadIdx.x;
    const int wave = tid >> 6;
    const int lane = tid & 63;
    const int bh = blockIdx.y;
    const int q0 = blockIdx.x * QROWS;
    const int lr = lane & 15;
    const int lg = lane >> 4;
    const float L2E = 1.4426950408889634f;

    const ushort* Qb = qh + ((size_t)bh * NSEQ + q0) * HDIM;
    const ushort* Kb = kh + (size_t)bh * NSEQ * HDIM;

    f16x8 qf0 = *(const f16x8*)(Qb + lr * HDIM + lg * 8);
    f16x8 qf1 = *(const f16x8*)(Qb + lr * HDIM + 32 + lg * 8);

    // -------- Phase 1: scores + online per-lane top-5 --------
    uint u00 = 0, u01 = 0, u02 = 0, u03 = 0, u04 = 0;
    uint u10 = 0, u11 = 0, u12 = 0, u13 = 0, u14 = 0;
    uint u20 = 0, u21 = 0, u22 = 0, u23 = 0, u24 = 0;
    uint u30 = 0, u31 = 0, u32 = 0, u33 = 0, u34 = 0;

    const int kwbase = wave * 256;
    const ushort* Kt0 = Kb + (size_t)kwbase * HDIM;
    f16x8 a0 = *(const f16x8*)(Kt0 + lr * HDIM + lg * 8);
    f16x8 a1 = *(const f16x8*)(Kt0 + lr * HDIM + 32 + lg * 8);

#pragma unroll
    for (int t = 0; t < 16; ++t) {
        f16x8 n0 = a0, n1 = a1;
        if (t < 15) {
            const ushort* Kn = Kb + (size_t)(kwbase + (t + 1) * 16) * HDIM;
            n0 = *(const f16x8*)(Kn + lr * HDIM + lg * 8);
            n1 = *(const f16x8*)(Kn + lr * HDIM + 32 + lg * 8);
        }
        f32x4 acc = {0.f, 0.f, 0.f, 0.f};
        acc = __builtin_amdgcn_mfma_f32_16x16x32_f16(a0, qf0, acc, 0, 0, 0);
        acc = __builtin_amdgcn_mfma_f32_16x16x32_f16(a1, qf1, acc, 0, 0, 0);
        const uint col = (uint)(kwbase + t * 16 + lg * 4);
        uint w0 = (uint)f2h(acc[0]) | ((uint)f2h(acc[1]) << 16);
        uint w1 = (uint)f2h(acc[2]) | ((uint)f2h(acc[3]) << 16);
        w0 = sm2(w0); w1 = sm2(w1);
        uint2 pk = {w0, w1};
        *(uint2*)&Sbuf[lr * SROWU + col] = pk;
        uint p;
        p = (w0 << 16) | col;               INS5(u00, u01, u02, u03, u04, p);
        p = (w0 & 0xFFFF0000u) | (col + 1); INS5(u10, u11, u12, u13, u14, p);
        p = (w1 << 16) | (col + 2);         INS5(u20, u21, u22, u23, u24, p);
        p = (w1 & 0xFFFF0000u) | (col + 3); INS5(u30, u31, u32, u33, u34, p);
        a0 = n0; a1 = n1;
    }

    // merge 4 top-5s -> stream top-5 in u00..u04
    INS5(u00, u01, u02, u03, u04, u10); INS5(u00, u01, u02, u03, u04, u11);
    INS5(u00, u01, u02, u03, u04, u12); INS5(u00, u01, u02, u03, u04, u13);
    INS5(u00, u01, u02, u03, u04, u14);
    INS5(u00, u01, u02, u03, u04, u20); INS5(u00, u01, u02, u03, u04, u21);
    INS5(u00, u01, u02, u03, u04, u22); INS5(u00, u01, u02, u03, u04, u23);
    INS5(u00, u01, u02, u03, u04, u24);
    INS5(u00, u01, u02, u03, u04, u30); INS5(u00, u01, u02, u03, u04, u31);
    INS5(u00, u01, u02, u03, u04, u32); INS5(u00, u01, u02, u03, u04, u33);
    INS5(u00, u01, u02, u03, u04, u34);

    {
        const int sidx = wave * 4 + lg;              // stream id 0..31
        const int cb = lr * CSTRIDE + sidx;
        cand[cb +   0] = u00;
        cand[cb +  33] = u01;
        cand[cb +  66] = u02;
        cand[cb +  99] = u03;
        cand[cb + 132] = u04;
    }
    __syncthreads();

    // -------- Phase 2: 2 rows per wave, one per 32-lane half --------
    const int halfid = lane >> 5;
    const int s = lane & 31;
    const int qrA = wave * 2, qrB = qrA + 1;
    const int qrMy = qrA + halfid;
    const int b = bh >> 3, hh = bh & 7;

    uint c0, c1, c2, c3, c4;
    {
        const int cb = qrMy * CSTRIDE + s;
        c0 = cand[cb]; c1 = cand[cb + 33]; c2 = cand[cb + 66];
        c3 = cand[cb + 99]; c4 = cand[cb + 132];
    }

    // row max per half (candidate c0 = stream max)
    uint mx = c0;
#pragma unroll
    for (int off = 1; off <= 16; off <<= 1) mx = max(mx, (uint)__shfl_xor((int)mx, off));
    const float Mv = sort2f(mx >> 16);

    // binary search on the 160-candidate sample (both rows share iterations)
    uint lo = 0, hi = 0xFFFFu;
#pragma unroll
    for (int it = 0; it < 16; ++it) {
        uint mid = (lo + hi + 1) >> 1, M = mid << 16;
        int cnt = (c0 >= M) + (c1 >= M) + (c2 >= M) + (c3 >= M) + (c4 >= M);
        ull m0 = __ballot(cnt & 1), m1 = __ballot(cnt & 2), m2 = __ballot(cnt & 4);
        int tA = (int)__popcll(m0 & 0xFFFFFFFFull) + 2 * (int)__popcll(m1 & 0xFFFFFFFFull)
               + 4 * (int)__popcll(m2 & 0xFFFFFFFFull);
        int tB = (int)__popcll(m0 >> 32) + 2 * (int)__popcll(m1 >> 32) + 4 * (int)__popcll(m2 >> 32);
        bool ge = (halfid ? tB : tA) >= LSEL;
        lo = ge ? mid : lo;
        hi = ge ? hi : mid - 1;
    }
    uint th = lo << 16;

    // broadcasts needed by possible slow paths (pre-divergence)
    const float MvA = __shfl(Mv, 0), MvB = __shfl(Mv, 32);
    const uint loA = (uint)__shfl((int)lo, 0), loB = (uint)__shfl((int)lo, 32);

    // exactness: sample complete iff no stream's 5th-largest >= t-hat
    ull mm = __ballot(c4 >= th);
    const bool missA = (mm & 0xFFFFFFFFull) != 0ull;
    const bool missB = (mm >> 32) != 0ull;
    const bool myMiss = halfid ? missB : missA;

    float wsMy = 1.f;
    int nkMy = 0;

    if (!myMiss) {   // fast path: selected set is within candidate top-4s
        int cs = (c0 >= th) + (c1 >= th) + (c2 >= th) + (c3 >= th);
        ull HB = halfid ? 0xFFFFFFFF00000000ull : 0x00000000FFFFFFFFull;
        ull below = ((1ull << lane) - 1ull) & HB;
        int pre = 0, tot = 0;
#pragma unroll
        for (int bb = 0; bb < 3; ++bb) {
            ull m = __ballot((cs >> bb) & 1);
            pre += (int)__popcll(m & below) << bb;
            tot += (int)__popcll(m & HB) << bb;
        }
        float wp = 0.f;
        uint cc0 = c0, cc1 = c1, cc2 = c2, cc3 = c3;
#pragma unroll
        for (int i = 0; i < 4; ++i) {
            uint ci = (i == 0) ? cc0 : (i == 1) ? cc1 : (i == 2) ? cc2 : cc3;
            if (ci >= th) {
                ushort w16 = f2h(exp2f((sort2f(ci >> 16) - Mv) * L2E));
                int pos = pre + i;
                if (pos < MAXL) { sel[qrMy][pos] = ((uint)w16 << 16) | (ci & 0xFFFFu); wp += h16f(w16); }
            }
        }
#pragma unroll
        for (int off = 1; off <= 16; off <<= 1) wp += __shfl_xor(wp, off);
        wsMy = wp;
        nkMy = (tot < MAXL) ? tot : MAXL;
    }

    if (missA) {     // rare: full-row exact path for row A (whole wave)
        const ushort* Sr = &Sbuf[qrA * SROWU];
        uint ft = full_thr(Sr, lane, loA);
        uint thv = ft << 16;
        int cs = recount(Sr, lane, thv);
        ull below64 = (1ull << lane) - 1ull;
        int preS = 0, totS = 0;
#pragma unroll
        for (int bb = 0; bb < 6; ++bb) {
            ull m = __ballot((cs >> bb) & 1);
            preS += (int)__popcll(m & below64) << bb;
            totS += (int)__popcll(m) << bb;
        }
        float wa = extract_big(Sr, lane, thv, MvA, preS, &sel[qrA][0]);
        if (halfid == 0) { wsMy = wa; nkMy = (totS < MAXL) ? totS : MAXL; }
    }
    if (missB) {
        const ushort* Sr = &Sbuf[qrB * SROWU];
        uint ft = full_thr(Sr, lane, loB);
        uint thv = ft << 16;
        int cs = recount(Sr, lane, thv);
        ull below64 = (1ull << lane) - 1ull;
        int preS = 0, totS = 0;
#pragma unroll
        for (int bb = 0; bb < 6; ++bb) {
            ull m = __ballot((cs >> bb) & 1);
            preS += (int)__popcll(m & below64) << bb;
            totS += (int)__popcll(m) << bb;
        }
        float wb = extract_big(Sr, lane, thv, MvB, preS, &sel[qrB][0]);
        if (halfid == 1) { wsMy = wb; nkMy = (totS < MAXL) ? totS : MAXL; }
    }

    asm volatile("s_waitcnt lgkmcnt(0)" ::: "memory");

    // -------- sparse PV: half = row, 32 lanes x half2 dims, 8-deep unroll ----
    const __half2* V2 = reinterpret_cast<const __half2*>(vh + (size_t)bh * NSEQ * HDIM);
    const int dp = lane & 31;
    const uint* selp = &sel[qrMy][0];

    float ox = 0.f, oy = 0.f;
    int j = 0;
    for (; j + 8 <= nkMy; j += 8) {
        uint e[8];
        *(uint4*)&e[0] = *(const uint4*)(selp + j);
        *(uint4*)&e[4] = *(const uint4*)(selp + j + 4);
        float2 vv[8];
        float ww[8];
#pragma unroll
        for (int i2 = 0; i2 < 8; ++i2) {
            int idx = (int)(e[i2] & 0xFFFFu);
            ww[i2] = h16f((ushort)(e[i2] >> 16));
            vv[i2] = __half22float2(V2[(size_t)idx * 32 + dp]);
        }
#pragma unroll
        for (int i2 = 0; i2 < 8; ++i2) { ox += ww[i2] * vv[i2].x; oy += ww[i2] * vv[i2].y; }
    }
    for (; j < nkMy; ++j) {
        uint e = selp[j];
        int idx = (int)(e & 0xFFFFu);
        float w = h16f((ushort)(e >> 16));
        float2 v0 = __half22float2(V2[(size_t)idx * 32 + dp]);
        ox += w * v0.x; oy += w * v0.y;
    }

    const float inv = 1.f / wsMy;
    uint opk = (uint)f2h(ox * inv) | ((uint)f2h(oy * inv) << 16);
    *(uint*)(ao + ((size_t)(b * NSEQ) + q0 + qrMy) * DMODEL + hh * HDIM + dp * 2) = opk;
}

// ---------------------------------------------------------------------------
// LN: out = LN(fc_raw + resid) * g + b ; 4 waves/block, 1 row/wave
// ---------------------------------------------------------------------------
__global__ __launch_bounds__(256) void ln_kernel(
    const float* __restrict__ fcr, const float* __restrict__ resid,
    const float* __restrict__ g, const float* __restrict__ bta, float* __restrict__ out)
{
    const int row = blockIdx.x * 4 + (threadIdx.x >> 6);
    const int lane = threadIdx.x & 63;
    const size_t base = (size_t)row * DMODEL + lane * 8;
    float4 xa = *(const float4*)(fcr + base);
    float4 xb = *(const float4*)(fcr + base + 4);
    float4 ra = *(const float4*)(resid + base);
    float4 rb = *(const float4*)(resid + base + 4);
    xa.x += ra.x; xa.y += ra.y; xa.z += ra.z; xa.w += ra.w;
    xb.x += rb.x; xb.y += rb.y; xb.z += rb.z; xb.w += rb.w;
    float sum = xa.x + xa.y + xa.z + xa.w + xb.x + xb.y + xb.z + xb.w;
    float sq = xa.x * xa.x + xa.y * xa.y + xa.z * xa.z + xa.w * xa.w
             + xb.x * xb.x + xb.y * xb.y + xb.z * xb.z + xb.w * xb.w;
#pragma unroll
    for (int off = 32; off >= 1; off >>= 1) {
        sum += __shfl_xor(sum, off);
        sq += __shfl_xor(sq, off);
    }
    float mean = sum * (1.f / 512.f);
    float var = sq * (1.f / 512.f) - mean * mean;
    float rstd = rsqrtf(var + 1e-6f);
    float4 ga = *(const float4*)(g + lane * 8);
    float4 gb = *(const float4*)(g + lane * 8 + 4);
    float4 ba = *(const float4*)(bta + lane * 8);
    float4 bb = *(const float4*)(bta + lane * 8 + 4);
    float4 oa, ob;
    oa.x = (xa.x - mean) * rstd * ga.x + ba.x;
    oa.y = (xa.y - mean) * rstd * ga.y + ba.y;
    oa.z = (xa.z - mean) * rstd * ga.z + ba.z;
    oa.w = (xa.w - mean) * rstd * ga.w + ba.w;
    ob.x = (xb.x - mean) * rstd * gb.x + bb.x;
    ob.y = (xb.y - mean) * rstd * gb.y + bb.y;
    ob.z = (xb.z - mean) * rstd * gb.z + bb.z;
    ob.w = (xb.w - mean) * rstd * gb.w + bb.w;
    *(float4*)(out + base) = oa;
    *(float4*)(out + base + 4) = ob;
}

extern "C" void kernel_launch(void* const* d_in, const int* in_sizes, int n_in,
                              void* d_out, int out_size, void* d_ws, size_t ws_size,
                              hipStream_t stream)
{
    (void)in_sizes; (void)n_in; (void)out_size; (void)ws_size;

    const float* q   = (const float*)d_in[0];
    const float* k   = (const float*)d_in[1];
    const float* v   = (const float*)d_in[2];
    const float* Wq  = (const float*)d_in[3];
    const float* Wk  = (const float*)d_in[4];
    const float* Wv  = (const float*)d_in[5];
    const float* Wfc = (const float*)d_in[6];
    const float* g   = (const float*)d_in[7];
    const float* b   = (const float*)d_in[8];
    float* out = (float*)d_out;

    const size_t SZ = (size_t)BATCH * NSEQ * DMODEL;      // 4,194,304
    const size_t WSZ = (size_t)DMODEL * DMODEL;           // 262,144
    ushort* w16 = (ushort*)d_ws;
    ushort* q16 = w16;
    ushort* k16 = w16 + SZ;
    ushort* v16 = w16 + 2 * SZ;
    ushort* Wt  = w16 + 3 * SZ;                           // 4 matrices
    ushort* qh  = Wt + 4 * WSZ;
    ushort* kh  = qh + SZ;
    ushort* vh  = kh + SZ;
    ushort* ao  = vh + SZ;
    float* fc_raw = (float*)d_ws;   // overlays q16+k16 (dead by fc time)

    cvtA_kernel<<<dim3(2048, 3), 256, 0, stream>>>(q, k, v, q16, k16, v16);
    cvtW_kernel<<<dim3(64, 4), 256, 0, stream>>>(Wq, Wk, Wv, Wfc, Wt);
    hgemm_kernel<0><<<dim3(128, 3), 256, 0, stream>>>(q16, k16, v16, Wt, qh, kh, vh, nullptr);
    attn_kernel<<<dim3(NSEQ / QROWS, BATCH * NHEAD), 512, 0, stream>>>(qh, kh, vh, ao);
    hgemm_kernel<1><<<dim3(128, 1), 256, 0, stream>>>(ao, nullptr, nullptr, Wt, nullptr, nullptr, nullptr, fc_raw);
    ln_kernel<<<(BATCH * NSEQ) / 4, 256, 0, stream>>>(fc_raw, q, g, b, out);
}